// Round 13
// baseline (317.048 us; speedup 1.0000x reference)
//
#include <hip/hip_runtime.h>
#include <hip/hip_bf16.h>
#include <math.h>

// ---------------------------------------------------------------------------
// ModelFC_49134425866355 on MI355X (gfx950)
//
// out0[row] = dot(LN(gelu(E@W1+b1))*g+b, W2[:,sel]) + b2[sel]
//           = rstd*(D - mu*Gw) + Bw     (algebraic LN+GEMV fusion)
//
// r24 change vs r22 (305.7us measured; gemm1p 103.9; prefix ~190):
// KEY FACT: sel = argmax(own[511]) depends ONLY on row 511. So gemm1p's
// u/Gw/Bw dependency needs just a one-block row-511 kernel (row511_fin,
// r22-verbatim math), and the full 512-row own_lnlog becomes 512 rider
// blocks INSIDE the gemm launch (gemm_own: blocks 0-511 = own rows,
// 512-3583 = gemm tiles). Rider and gemm blocks touch disjoint memory
// (no spin, no dispatch-order assumption -> G16-safe); own_lnlog's
// standalone duration is absorbed into gemm's MFMA-bound window.
// hpart<->pS* union DISSOLVED (hpart live during gemm_own): ws 65.7->70 MB.
// Rider math = r20's 256-thread row body (passed r8); row511_fin = r22's
// 512-thread body (passed r9); gemm loop untouched.
// 4 kernels: prep_duo(+cvt) | row511_fin | gemm_own | out_scores.
// (r27 = r24 resubmitted verbatim: rounds 10-12 all failed with
// GPUAcquisitionTimeout before any measurement.)
// ---------------------------------------------------------------------------

typedef __bf16 bf16_t;
typedef __bf16  bf16x2  __attribute__((ext_vector_type(2)));
typedef __bf16  bf16x8  __attribute__((ext_vector_type(8)));
typedef float   floatx4 __attribute__((ext_vector_type(4)));

__device__ __forceinline__ float gelu_exact(float x) {
    return 0.5f * x * (1.0f + erff(x * 0.7071067811865475f));
}
// tanh-form gelu via sigmoid; |err|<~1e-3, below bf16 rounding of bulk path.
__device__ __forceinline__ float gelu_fast(float x) {
    const float z = x * (1.0f + 0.044715f * x * x);
    return __fdividef(x, 1.0f + __expf(-1.5957691216f * z));
}

// async global->LDS, 16B per lane; lds base wave-uniform (HW adds lane*16).
// OFFSET ARG STAYS 0 — nonzero immediate is unverified and broke round 5.
__device__ __forceinline__ void gl_lds16(const void* g, void* l) {
    __builtin_amdgcn_global_load_lds(
        (const __attribute__((address_space(1))) void*)g,
        (__attribute__((address_space(3))) void*)l, 16, 0, 0);
}

// ---------------------------------------------------------------------------
// prep_duo: [0,288) tr_w1 | [288,1056) own_h | [1056,13344) E->bf16 cvt
// (verbatim from r22, measured-good)
// ---------------------------------------------------------------------------
__global__ __launch_bounds__(256) void prep_duo(
        const float* __restrict__ E, const float* __restrict__ W1,
        bf16_t* __restrict__ W1t, float* __restrict__ hpart,
        bf16_t* __restrict__ Ebf) {
    __shared__ alignas(16) char smemc[16640];   // max(sT 64x65 fp32, sE 6KB)
    const int bid = blockIdx.x;
    const int tid = threadIdx.x;

    if (bid >= 1056) {                  // ---- E -> bf16 (25,165,824 elems)
        const int cb = bid - 1056;      // 0..12287
        const size_t base = ((size_t)cb * 256 + tid) * 8;
        const float4 v0 = *(const float4*)(E + base);
        const float4 v1 = *(const float4*)(E + base + 4);
        bf16x8 o;
        o[0] = (bf16_t)v0.x; o[1] = (bf16_t)v0.y;
        o[2] = (bf16_t)v0.z; o[3] = (bf16_t)v0.w;
        o[4] = (bf16_t)v1.x; o[5] = (bf16_t)v1.y;
        o[6] = (bf16_t)v1.z; o[7] = (bf16_t)v1.w;
        *(bf16x8*)(Ebf + base) = o;
        return;
    }

    if (bid < 288) {                    // ---- tr_w1: 64x64 LDS-tiled transpose
        float* sT = (float*)smemc;      // [64][65]
        const int bk = bid % 12, bn = bid / 12;
        const int k0 = bk * 64, n0 = bn * 64;
        #pragma unroll
        for (int i = 0; i < 16; ++i) {
            const int idx = tid + i * 256;
            const int kk = idx >> 6, nn = idx & 63;
            sT[kk * 65 + nn] = W1[(size_t)(k0 + kk) * 1536 + n0 + nn];
        }
        __syncthreads();
        // vectorized bf16x2 stores: idx covers (nn, kk-pair)
        #pragma unroll
        for (int i = 0; i < 8; ++i) {
            const int idx = tid + i * 256;   // 0..2047
            const int nn = idx >> 5;         // 0..63
            const int kp = (idx & 31) * 2;   // 0,2,..,62
            bf16x2 v;
            v[0] = (bf16_t)sT[kp * 65 + nn];
            v[1] = (bf16_t)sT[(kp + 1) * 65 + nn];
            *(bf16x2*)(W1t + (size_t)(n0 + nn) * 768 + k0 + kp) = v;
        }
    } else {                            // ---- own_h: hpart[kq][512][1536]
        float* sE = (float*)smemc;      // [8][192]
        const int b  = bid - 288;       // 0..767
        const int a  = b & 63;
        const int rest = b >> 6;        // 0..11
        const int by = rest % 3, kq = rest / 3;

        const float* Ebase = E + (size_t)(520 * a) * 768 + kq * 192;
        for (int idx = tid; idx < 1536; idx += 256) {
            const int row = idx / 192, i = idx - row * 192;
            sE[idx] = Ebase[(size_t)row * 768 + i];
        }
        __syncthreads();

        const int c0 = by * 512 + tid * 2;
        const float* w1p = W1 + (size_t)(kq * 192) * 1536 + c0;
        float ax[8] = {}, ay[8] = {};
        for (int k = 0; k < 192; ++k) {
            const float2 w = *(const float2*)(w1p + (size_t)k * 1536);
            #pragma unroll
            for (int j = 0; j < 8; ++j) {
                const float e = sE[j * 192 + k];   // LDS broadcast
                ax[j] += w.x * e;
                ay[j] += w.y * e;
            }
        }
        #pragma unroll
        for (int j = 0; j < 8; ++j)
            *(float2*)(hpart + (size_t)(kq * 512 + a * 8 + j) * 1536 + c0)
                = make_float2(ax[j], ay[j]);
    }
}

// ---------------------------------------------------------------------------
// row511_fin: ONE block, 512 threads. Row-511 gelu+LN+logits (r22-verbatim
// math) -> argmax (first-max) -> sel -> u / Gw / Bw. No VG output writes
// (the rider block for row 511 writes those).
// ---------------------------------------------------------------------------
__global__ __launch_bounds__(512) void row511_fin(
        const float* __restrict__ hpart, const float* __restrict__ b1,
        const float* __restrict__ lng,  const float* __restrict__ lnb,
        const float* __restrict__ W2,   const float* __restrict__ b2,
        float* __restrict__ u, float* __restrict__ gwbw) {
    __shared__ float srow[1536];
    __shared__ float red16[16];
    __shared__ float redl[384];
    __shared__ float slog[128];
    __shared__ int   ssel;
    const int row = 511, tid = threadIdx.x;
    const int lane = tid & 63, wv = tid >> 6;   // wv 0..7

    float x[3];
    #pragma unroll
    for (int i = 0; i < 3; ++i) {
        const int c = tid + i * 512;
        x[i] = gelu_exact(hpart[(size_t)row * 1536 + c]
                        + hpart[(size_t)(512 + row) * 1536 + c]
                        + hpart[(size_t)(1024 + row) * 1536 + c]
                        + hpart[(size_t)(1536 + row) * 1536 + c] + b1[c]);
    }
    float s = x[0] + x[1] + x[2];
    #pragma unroll
    for (int o = 32; o > 0; o >>= 1) s += __shfl_xor(s, o, 64);
    if (lane == 0) red16[wv] = s;
    __syncthreads();
    float mu = 0.f;
    #pragma unroll
    for (int i = 0; i < 8; ++i) mu += red16[i];
    mu *= (1.0f / 1536.0f);

    float s2 = 0.f;
    #pragma unroll
    for (int i = 0; i < 3; ++i) { float d = x[i] - mu; s2 += d * d; }
    #pragma unroll
    for (int o = 32; o > 0; o >>= 1) s2 += __shfl_xor(s2, o, 64);
    if (lane == 0) red16[8 + wv] = s2;
    __syncthreads();
    float v2 = 0.f;
    #pragma unroll
    for (int i = 0; i < 8; ++i) v2 += red16[8 + i];
    const float rstd = rsqrtf(v2 * (1.0f / 1536.0f) + 1e-12f);

    #pragma unroll
    for (int i = 0; i < 3; ++i) {
        const int c = tid + i * 512;
        srow[c] = (x[i] - mu) * rstd * lng[c] + lnb[c];
    }
    __syncthreads();

    // logits: (d, ks) = (128, 4); 384 k-iters each (r22-verbatim)
    const int d  = tid & 127;
    const int ks = tid >> 7;                  // 0..3
    const int dd = d < 100 ? d : 99;
    float acc = (ks == 0) ? b2[dd] : 0.0f;
    const float* hr  = srow + ks * 384;
    const float* w2p = W2 + (size_t)(ks * 384) * 100 + dd;
    #pragma unroll 8
    for (int k = 0; k < 384; ++k)
        acc += hr[k] * w2p[(size_t)k * 100];
    if (ks) redl[(ks - 1) * 128 + d] = acc;
    __syncthreads();
    if (ks == 0) {
        const float tot = acc + redl[d] + redl[128 + d] + redl[256 + d];
        slog[d] = (d < 100) ? tot : -INFINITY;
    }
    __syncthreads();

    if (wv == 0) {       // argmax only (first-max tie-break)
        const float v0 = slog[lane], v1 = slog[lane + 64];
        float bv; int bi;
        if (v0 >= v1) { bv = v0; bi = lane; } else { bv = v1; bi = lane + 64; }
        #pragma unroll
        for (int o = 1; o < 64; o <<= 1) {
            const float vo = __shfl_xor(bv, o, 64);
            const int   io = __shfl_xor(bi, o, 64);
            if (vo > bv || (vo == bv && io < bi)) { bv = vo; bi = io; }
        }
        if (lane == 0) ssel = bi;
    }
    __syncthreads();

    const int sel = ssel;
    float gw = 0.f, bw = 0.f;
    #pragma unroll
    for (int c = tid; c < 1536; c += 512) {
        const float wv2 = W2[(size_t)c * 100 + sel];
        const float uu = lng[c] * wv2;
        u[c] = uu;
        gw += uu;
        bw += lnb[c] * wv2;
    }
    #pragma unroll
    for (int o = 32; o > 0; o >>= 1) {
        gw += __shfl_xor(gw, o, 64);
        bw += __shfl_xor(bw, o, 64);
    }
    if (lane == 0) { red16[wv] = gw; red16[8 + wv] = bw; }
    __syncthreads();
    if (tid == 0) {
        float G = 0.f, B = 0.f;
        #pragma unroll
        for (int i = 0; i < 8; ++i) { G += red16[i]; B += red16[8 + i]; }
        gwbw[0] = G;
        gwbw[1] = B + b2[sel];
    }
}

// ---------------------------------------------------------------------------
// gemm_own: blocks [0,512) = own-row riders (gelu+LN+logits+softmax/argmax,
// r20's 256-thread math, writes VG_scores/VG_scores_index); blocks
// [512,3584) = gemm tiles (verbatim r14 gemm1p, 745 TF measured).
// Rider and gemm blocks are fully independent (disjoint reads/writes) —
// no ordering or co-residency assumption.
// ---------------------------------------------------------------------------
__global__ __launch_bounds__(256) void gemm_own(
        const bf16_t* __restrict__ A, const bf16_t* __restrict__ Bt,
        const float* __restrict__ bias, const float* __restrict__ u,
        float* __restrict__ pS1, float* __restrict__ pS2,
        float* __restrict__ pD,
        const float* __restrict__ hpart, const float* __restrict__ lng,
        const float* __restrict__ lnb,  const float* __restrict__ W2,
        const float* __restrict__ b2,   float* __restrict__ out) {
    constexpr int K = 768;
    __shared__ alignas(16) char smem[36864];
    const int bid = blockIdx.x;
    const int tid = threadIdx.x;

    if (bid < 512) {                    // ======== own-row rider block ========
        const int row = bid;
        float* srow = (float*)smem;              // 1536 f  (6144 B)
        float* red8 = (float*)(smem + 6144);     // 8 f
        float* redl = (float*)(smem + 6208);     // 128 f
        float* slog = (float*)(smem + 6720);     // 128 f
        const int lane = tid & 63, wv = tid >> 6;  // wv 0..3

        float x[6];
        #pragma unroll
        for (int i = 0; i < 6; ++i) {
            const int c = tid + i * 256;
            x[i] = gelu_exact(hpart[(size_t)row * 1536 + c]
                            + hpart[(size_t)(512 + row) * 1536 + c]
                            + hpart[(size_t)(1024 + row) * 1536 + c]
                            + hpart[(size_t)(1536 + row) * 1536 + c] + bias[c]);
        }
        float s = 0.f;
        #pragma unroll
        for (int i = 0; i < 6; ++i) s += x[i];
        #pragma unroll
        for (int o = 32; o > 0; o >>= 1) s += __shfl_xor(s, o, 64);
        if (lane == 0) red8[wv] = s;
        __syncthreads();
        const float mu = (red8[0] + red8[1] + red8[2] + red8[3]) * (1.0f / 1536.0f);

        float s2 = 0.f;
        #pragma unroll
        for (int i = 0; i < 6; ++i) { float dx = x[i] - mu; s2 += dx * dx; }
        #pragma unroll
        for (int o = 32; o > 0; o >>= 1) s2 += __shfl_xor(s2, o, 64);
        if (lane == 0) red8[4 + wv] = s2;
        __syncthreads();
        const float rstd = rsqrtf((red8[4] + red8[5] + red8[6] + red8[7])
                                  * (1.0f / 1536.0f) + 1e-12f);

        #pragma unroll
        for (int i = 0; i < 6; ++i) {
            const int c = tid + i * 256;
            srow[c] = (x[i] - mu) * rstd * lng[c] + lnb[c];
        }
        __syncthreads();

        // logits: (d, ks) = (128, 2); 768 k-iters (r20-verbatim)
        const int d  = tid & 127;
        const int ks = tid >> 7;
        const int dd = d < 100 ? d : 99;
        float acc = ks ? 0.0f : b2[dd];
        const float* hr = srow + ks * 768;
        for (int k = 0; k < 768; ++k)
            acc += hr[k] * W2[(size_t)(ks * 768 + k) * 100 + dd];
        if (ks) redl[d] = acc;
        __syncthreads();
        if (!ks) slog[d] = (d < 100) ? (acc + redl[d]) : -INFINITY;
        __syncthreads();

        if (wv == 0) {   // softmax max-prob + argmax (first-max tie-break)
            const float v0 = slog[lane], v1 = slog[lane + 64];
            float bv; int bi;
            if (v0 >= v1) { bv = v0; bi = lane; } else { bv = v1; bi = lane + 64; }
            #pragma unroll
            for (int o = 1; o < 64; o <<= 1) {
                const float vo = __shfl_xor(bv, o, 64);
                const int   io = __shfl_xor(bi, o, 64);
                if (vo > bv || (vo == bv && io < bi)) { bv = vo; bi = io; }
            }
            float e = expf(v0 - bv) + expf(v1 - bv);   // exp(-inf)=0 pads
            #pragma unroll
            for (int o = 32; o > 0; o >>= 1) e += __shfl_xor(e, o, 64);
            if (lane == 0) {
                out[262144 + row] = 1.0f / e;          // VG_scores
                out[262656 + row] = (float)bi;         // VG_scores_index
            }
        }
        return;
    }

    // ======== gemm tile block (verbatim r14 loop) ========
    bf16_t* sA = (bf16_t*)smem;                // [128][64] bf16, swizzled
    bf16_t* sB = (bf16_t*)(smem + 16384);      // [128][64] bf16, swizzled

    const int g = bid - 512;                   // 0..3071
    const int xcd  = g & 7;
    const int slot = g >> 3;
    const int bx = slot % 12;
    const int by = (slot / 12) * 8 + xcd;

    const int lane = tid & 63;
    const int wave = tid >> 6;
    const int wr = wave >> 1, wc = wave & 1;
    const int m0 = by * 128;
    const int n0 = bx * 128;
    const int q  = lane >> 4;
    const int l15 = lane & 15;

    const bf16_t* gA[4]; bf16_t* lA[4];
    const bf16_t* gB[4]; bf16_t* lB[4];
    #pragma unroll
    for (int c = 0; c < 4; ++c) {
        const int s    = c * 256 + tid;
        const int row  = s >> 3;
        const int col  = s & 7;
        const int gcol = col ^ (row & 7);
        gA[c] = A  + (size_t)(m0 + row) * K + gcol * 8;
        lA[c] = sA + (c * 256 + wave * 64) * 8;
        gB[c] = Bt + (size_t)(n0 + row) * K + gcol * 8;
        lB[c] = sB + (c * 256 + wave * 64) * 8;
    }
    const bf16_t* rA[4]; const bf16_t* rB[4];
    #pragma unroll
    for (int t4 = 0; t4 < 4; ++t4) {
        rA[t4] = sA + (wr * 64 + t4 * 16 + l15) * 64;
        rB[t4] = sB + (wc * 64 + t4 * 16 + l15) * 64;
    }
    const int c0 = ((q)     ^ (lane & 7)) * 8;   // ks=0 fragment offset
    const int c1 = ((4 + q) ^ (lane & 7)) * 8;   // ks=1 fragment offset

    floatx4 acc[4][4] = {};

    #pragma unroll
    for (int kt = 0; kt < 12; ++kt) {
        const int k0 = kt * 64;
        __syncthreads();   // prev compute done before LDS overwrite
        #pragma unroll
        for (int c = 0; c < 4; ++c) gl_lds16(gB[c] + k0, lB[c]);
        #pragma unroll
        for (int c = 0; c < 4; ++c) gl_lds16(gA[c] + k0, lA[c]);
        __syncthreads();   // drain DMA, then barrier

        #pragma unroll
        for (int ks = 0; ks < 2; ++ks) {
            const int co = ks ? c1 : c0;
            bf16x8 af[4], bfr[4];
            #pragma unroll
            for (int t4 = 0; t4 < 4; ++t4) {
                af[t4]  = *(const bf16x8*)(rA[t4] + co);
                bfr[t4] = *(const bf16x8*)(rB[t4] + co);
            }
            #pragma unroll
            for (int mt = 0; mt < 4; ++mt)
                #pragma unroll
                for (int nt = 0; nt < 4; ++nt)
                    acc[mt][nt] = __builtin_amdgcn_mfma_f32_16x16x32_bf16(
                        af[mt], bfr[nt], acc[mt][nt], 0, 0, 0);
        }
    }

    // ---- stats epilogue via LDS (low VGPR). C/D layout: col=l15, row=q*4+r.
    __syncthreads();                       // all tile ds_reads done
    bf16_t* sh = (bf16_t*)smem;            // [128][130] bf16 = 33280 B
    float*  su = (float*)(smem + 33280);   // u[n0..n0+127]          512 B
    float*  sp = (float*)(smem + 33792);   // [256][3] partials     3072 B

    if (tid < 128) su[tid] = u[n0 + tid];
    float bias4[4];
    #pragma unroll
    for (int nt = 0; nt < 4; ++nt) bias4[nt] = bias[n0 + wc * 64 + nt * 16 + l15];

    #pragma unroll
    for (int mt = 0; mt < 4; ++mt)
        #pragma unroll
        for (int nt = 0; nt < 4; ++nt)
            #pragma unroll
            for (int r = 0; r < 4; ++r) {
                const int rowl = wr * 64 + mt * 16 + q * 4 + r;
                const int coll = wc * 64 + nt * 16 + l15;
                sh[rowl * 130 + coll] = (bf16_t)gelu_fast(acc[mt][nt][r] + bias4[nt]);
            }
    __syncthreads();

    // phase 2: thread = (row, half); reduce 64 cols each
    {
        const int rowl = tid >> 1, half = tid & 1;
        const bf16_t* hp = sh + rowl * 130 + half * 64;
        const float*  up = su + half * 64;
        float s1 = 0.f, s2 = 0.f, dd = 0.f;
        #pragma unroll
        for (int c = 0; c < 64; ++c) {
            const float v = (float)hp[c];
            s1 += v; s2 += v * v; dd += v * up[c];
        }
        sp[tid * 3 + 0] = s1; sp[tid * 3 + 1] = s2; sp[tid * 3 + 2] = dd;
    }
    __syncthreads();
    if (tid < 128) {
        const float* p0 = sp + (2 * tid) * 3;
        const float* p1 = sp + (2 * tid + 1) * 3;
        const size_t idx = (size_t)bx * 32768 + (m0 + tid);
        pS1[idx] = p0[0] + p1[0];
        pS2[idx] = p0[1] + p1[1];
        pD[idx]  = p0[2] + p1[2];
    }
}

// ---------------------------------------------------------------------------
// out_scores: out[t*8+k] = rstd*(D - mu*Gw) + Bw   (32768 threads)
// ---------------------------------------------------------------------------
__global__ __launch_bounds__(256) void out_scores(
        const float* __restrict__ pS1, const float* __restrict__ pS2,
        const float* __restrict__ pD,  const float* __restrict__ gwbw,
        float* __restrict__ out) {
    const int t = blockIdx.x * 256 + threadIdx.x;   // 32768 exactly
    float s1 = 0.f, s2 = 0.f, d = 0.f;
    #pragma unroll
    for (int nt = 0; nt < 12; ++nt) {
        const size_t idx = (size_t)nt * 32768 + t;
        s1 += pS1[idx]; s2 += pS2[idx]; d += pD[idx];
    }
    const float mu   = s1 * (1.0f / 1536.0f);
    const float var  = s2 * (1.0f / 1536.0f) - mu * mu;
    const float rstd = rsqrtf(var + 1e-12f);
    const float v = rstd * (d - mu * gwbw[0]) + gwbw[1];
    const float4 f = make_float4(v, v, v, v);
    float4* o = (float4*)(out + (size_t)t * 8);
    o[0] = f; o[1] = f;
}

// ---------------------------------------------------------------------------
extern "C" void kernel_launch(void* const* d_in, const int* in_sizes, int n_in,
                              void* d_out, int out_size, void* d_ws, size_t ws_size,
                              hipStream_t stream) {
    const float* E   = (const float*)d_in[0];
    const float* W1  = (const float*)d_in[1];
    const float* b1  = (const float*)d_in[2];
    const float* lng = (const float*)d_in[3];
    const float* lnb = (const float*)d_in[4];
    const float* W2  = (const float*)d_in[5];
    const float* b2  = (const float*)d_in[6];
    float* out = (float*)d_out;

    char* w = (char*)d_ws;
    auto carve = [&](size_t bytes) {
        void* p = (void*)w;
        w += (bytes + 255) & ~(size_t)255;
        return p;
    };
    bf16_t* W1t   = (bf16_t*)carve((size_t)1536 * 768 * 2);    //  2.4 MB
    bf16_t* Ebf   = (bf16_t*)carve((size_t)32768 * 768 * 2);   // 50.3 MB
    float*  u     = (float*)carve(1536 * 4);
    float*  gwbw  = (float*)carve(256);
    // hpart now LIVE during gemm_own (rider blocks read it) -> no union.
    float*  hpart = (float*)carve((size_t)4 * 512 * 1536 * 4); // 12.6 MB
    float*  pS1   = (float*)carve((size_t)12 * 32768 * 4);     //  1.6 MB
    float*  pS2   = (float*)carve((size_t)12 * 32768 * 4);
    float*  pD    = (float*)carve((size_t)12 * 32768 * 4);     // total ~70 MB

    // 1) prep: W1 transpose + own-row k-partials + E->bf16 (fused grid)
    prep_duo<<<13344, 256, 0, stream>>>(E, W1, W1t, hpart, Ebf);
    // 2) row 511 only: gelu+LN+logits -> sel -> u/Gw/Bw (one block)
    row511_fin<<<1, 512, 0, stream>>>(hpart, b1, lng, lnb, W2, b2, u, gwbw);
    // 3) fused GEMM + 512 own-row rider blocks (VG outputs)
    gemm_own<<<3584, 256, 0, stream>>>(Ebf, W1t, b1, u, pS1, pS2, pD,
                                       hpart, lng, lnb, W2, b2, out);
    // 4) combine partials -> output 0
    out_scores<<<128, 256, 0, stream>>>(pS1, pS2, pD, gwbw, out);
}

// Round 15
// 301.946 us; speedup vs baseline: 1.0500x; 1.0500x over previous
//
#include <hip/hip_runtime.h>
#include <hip/hip_bf16.h>
#include <math.h>

// ---------------------------------------------------------------------------
// ModelFC_49134425866355 on MI355X (gfx950)
//
// out0[row] = dot(LN(gelu(E@W1+b1))*g+b, W2[:,sel]) + b2[sel]
//           = rstd*(D - mu*Gw) + Bw     (algebraic LN+GEMV fusion)
//
// r28 = r22 champion (305.7us) REVERT + one bit-identical prep_duo change.
// r24's rider merge regressed (gemm_own 123.5 vs gemm 103.9; total 317):
// own_lnlog standalone was only ~15us, riders diluted MfmaUtil 34->27.5.
// Change here: own_h goes 768 blocks x 512cols -> 256 blocks x 1536cols
// (6 cols/thread, 48 accs): 8 sE LDS broadcasts per k amortized over 3x
// FMAs, W1 L2 traffic 302->101 MB, E re-staging 3x less. Per-column k-sum
// order unchanged -> hpart BIT-IDENTICAL. All else r22-verbatim.
// 4 kernels: prep_duo(+cvt) | own_lnlog(+fin) | gemm1p | out_scores.
// (r29 = r28 resubmitted verbatim: round 14 failed with
// GPUAcquisitionTimeout before any measurement.)
// ---------------------------------------------------------------------------

typedef __bf16 bf16_t;
typedef __bf16  bf16x2  __attribute__((ext_vector_type(2)));
typedef __bf16  bf16x8  __attribute__((ext_vector_type(8)));
typedef float   floatx4 __attribute__((ext_vector_type(4)));

__device__ __forceinline__ float gelu_exact(float x) {
    return 0.5f * x * (1.0f + erff(x * 0.7071067811865475f));
}
// tanh-form gelu via sigmoid; |err|<~1e-3, below bf16 rounding of bulk path.
__device__ __forceinline__ float gelu_fast(float x) {
    const float z = x * (1.0f + 0.044715f * x * x);
    return __fdividef(x, 1.0f + __expf(-1.5957691216f * z));
}

// async global->LDS, 16B per lane; lds base wave-uniform (HW adds lane*16).
// OFFSET ARG STAYS 0 — nonzero immediate is unverified and broke round 5.
__device__ __forceinline__ void gl_lds16(const void* g, void* l) {
    __builtin_amdgcn_global_load_lds(
        (const __attribute__((address_space(1))) void*)g,
        (__attribute__((address_space(3))) void*)l, 16, 0, 0);
}

// ---------------------------------------------------------------------------
// prep_duo: [0,288) tr_w1 | [288,544) own_h (full-row) | [544,12832) cvt
// ---------------------------------------------------------------------------
__global__ __launch_bounds__(256) void prep_duo(
        const float* __restrict__ E, const float* __restrict__ W1,
        bf16_t* __restrict__ W1t, float* __restrict__ hpart,
        bf16_t* __restrict__ Ebf) {
    __shared__ alignas(16) char smemc[16640];   // max(sT 64x65 fp32, sE 6KB)
    const int bid = blockIdx.x;
    const int tid = threadIdx.x;

    if (bid >= 544) {                   // ---- E -> bf16 (25,165,824 elems)
        const int cb = bid - 544;       // 0..12287
        const size_t base = ((size_t)cb * 256 + tid) * 8;
        const float4 v0 = *(const float4*)(E + base);
        const float4 v1 = *(const float4*)(E + base + 4);
        bf16x8 o;
        o[0] = (bf16_t)v0.x; o[1] = (bf16_t)v0.y;
        o[2] = (bf16_t)v0.z; o[3] = (bf16_t)v0.w;
        o[4] = (bf16_t)v1.x; o[5] = (bf16_t)v1.y;
        o[6] = (bf16_t)v1.z; o[7] = (bf16_t)v1.w;
        *(bf16x8*)(Ebf + base) = o;
        return;
    }

    if (bid < 288) {                    // ---- tr_w1: 64x64 LDS-tiled transpose
        float* sT = (float*)smemc;      // [64][65]
        const int bk = bid % 12, bn = bid / 12;
        const int k0 = bk * 64, n0 = bn * 64;
        #pragma unroll
        for (int i = 0; i < 16; ++i) {
            const int idx = tid + i * 256;
            const int kk = idx >> 6, nn = idx & 63;
            sT[kk * 65 + nn] = W1[(size_t)(k0 + kk) * 1536 + n0 + nn];
        }
        __syncthreads();
        // vectorized bf16x2 stores: idx covers (nn, kk-pair)
        #pragma unroll
        for (int i = 0; i < 8; ++i) {
            const int idx = tid + i * 256;   // 0..2047
            const int nn = idx >> 5;         // 0..63
            const int kp = (idx & 31) * 2;   // 0,2,..,62
            bf16x2 v;
            v[0] = (bf16_t)sT[kp * 65 + nn];
            v[1] = (bf16_t)sT[(kp + 1) * 65 + nn];
            *(bf16x2*)(W1t + (size_t)(n0 + nn) * 768 + k0 + kp) = v;
        }
    } else {                            // ---- own_h: hpart[kq][512][1536]
        // 256 blocks: (a, kq); each covers ALL 1536 cols (6 cols/thread).
        // Per-column k-order identical to the 768-block version -> hpart
        // bit-identical; sE broadcasts amortized 3x, W1 traffic 3x lower.
        float* sE = (float*)smemc;      // [8][192]
        const int b  = bid - 288;       // 0..255
        const int a  = b & 63;
        const int kq = b >> 6;          // 0..3

        const float* Ebase = E + (size_t)(520 * a) * 768 + kq * 192;
        for (int idx = tid; idx < 1536; idx += 256) {
            const int row = idx / 192, i = idx - row * 192;
            sE[idx] = Ebase[(size_t)row * 768 + i];
        }
        __syncthreads();

        const int c0 = tid * 2;         // 0..510
        const float* w1p = W1 + (size_t)(kq * 192) * 1536 + c0;
        float ax0[8] = {}, ay0[8] = {};
        float ax1[8] = {}, ay1[8] = {};
        float ax2[8] = {}, ay2[8] = {};
        for (int k = 0; k < 192; ++k) {
            const float* wk = w1p + (size_t)k * 1536;
            const float2 w0 = *(const float2*)(wk);
            const float2 w1v = *(const float2*)(wk + 512);
            const float2 w2v = *(const float2*)(wk + 1024);
            #pragma unroll
            for (int j = 0; j < 8; ++j) {
                const float e = sE[j * 192 + k];   // LDS broadcast, shared x3
                ax0[j] += w0.x * e;  ay0[j] += w0.y * e;
                ax1[j] += w1v.x * e; ay1[j] += w1v.y * e;
                ax2[j] += w2v.x * e; ay2[j] += w2v.y * e;
            }
        }
        #pragma unroll
        for (int j = 0; j < 8; ++j) {
            float* hp = hpart + (size_t)(kq * 512 + a * 8 + j) * 1536 + c0;
            *(float2*)(hp)        = make_float2(ax0[j], ay0[j]);
            *(float2*)(hp + 512)  = make_float2(ax1[j], ay1[j]);
            *(float2*)(hp + 1024) = make_float2(ax2[j], ay2[j]);
        }
    }
}

// ---------------------------------------------------------------------------
// own_lnlog: per row (512 blocks x 512 threads):
//   h = gelu_exact(sum of 4 k-partials + b1); fp32 LN in LDS;
//   logits[100] via 4-way k-split GEMV; in-block softmax/argmax ->
//   VG_scores / VG_scores_index (exact first-max); block 511 additionally
//   computes sel-derived u / Gw / Bw (sel = its own argmax).
// (verbatim r22, measured-good)
// ---------------------------------------------------------------------------
__global__ __launch_bounds__(512) void own_lnlog(
        const float* __restrict__ hpart, const float* __restrict__ b1,
        const float* __restrict__ lng,  const float* __restrict__ lnb,
        const float* __restrict__ W2,   const float* __restrict__ b2,
        float* __restrict__ out, float* __restrict__ u,
        float* __restrict__ gwbw) {
    __shared__ float srow[1536];
    __shared__ float red16[16];
    __shared__ float redl[384];
    __shared__ float slog[128];
    __shared__ int   ssel;
    const int row = blockIdx.x, tid = threadIdx.x;
    const int lane = tid & 63, wv = tid >> 6;   // wv 0..7

    // ---- gelu(sum of partials + b1), 3 cols/thread
    float x[3];
    #pragma unroll
    for (int i = 0; i < 3; ++i) {
        const int c = tid + i * 512;
        x[i] = gelu_exact(hpart[(size_t)row * 1536 + c]
                        + hpart[(size_t)(512 + row) * 1536 + c]
                        + hpart[(size_t)(1024 + row) * 1536 + c]
                        + hpart[(size_t)(1536 + row) * 1536 + c] + b1[c]);
    }
    float s = x[0] + x[1] + x[2];
    #pragma unroll
    for (int o = 32; o > 0; o >>= 1) s += __shfl_xor(s, o, 64);
    if (lane == 0) red16[wv] = s;
    __syncthreads();
    float mu = 0.f;
    #pragma unroll
    for (int i = 0; i < 8; ++i) mu += red16[i];
    mu *= (1.0f / 1536.0f);

    float s2 = 0.f;
    #pragma unroll
    for (int i = 0; i < 3; ++i) { float d = x[i] - mu; s2 += d * d; }
    #pragma unroll
    for (int o = 32; o > 0; o >>= 1) s2 += __shfl_xor(s2, o, 64);
    if (lane == 0) red16[8 + wv] = s2;
    __syncthreads();
    float v2 = 0.f;
    #pragma unroll
    for (int i = 0; i < 8; ++i) v2 += red16[8 + i];
    const float rstd = rsqrtf(v2 * (1.0f / 1536.0f) + 1e-12f);

    #pragma unroll
    for (int i = 0; i < 3; ++i) {
        const int c = tid + i * 512;
        srow[c] = (x[i] - mu) * rstd * lng[c] + lnb[c];
    }
    __syncthreads();

    // ---- logits: (d, ks) = (128, 4); 384 k-iters each
    const int d  = tid & 127;
    const int ks = tid >> 7;                  // 0..3
    const int dd = d < 100 ? d : 99;
    float acc = (ks == 0) ? b2[dd] : 0.0f;
    const float* hr  = srow + ks * 384;
    const float* w2p = W2 + (size_t)(ks * 384) * 100 + dd;
    #pragma unroll 8
    for (int k = 0; k < 384; ++k)
        acc += hr[k] * w2p[(size_t)k * 100];
    if (ks) redl[(ks - 1) * 128 + d] = acc;
    __syncthreads();
    if (ks == 0) {
        const float tot = acc + redl[d] + redl[128 + d] + redl[256 + d];
        slog[d] = (d < 100) ? tot : -INFINITY;
    }
    __syncthreads();

    // ---- wave 0: softmax max-prob + argmax (first-max tie-break)
    if (wv == 0) {
        const float v0 = slog[lane], v1 = slog[lane + 64];
        float bv; int bi;
        if (v0 >= v1) { bv = v0; bi = lane; } else { bv = v1; bi = lane + 64; }
        #pragma unroll
        for (int o = 1; o < 64; o <<= 1) {
            const float vo = __shfl_xor(bv, o, 64);
            const int   io = __shfl_xor(bi, o, 64);
            if (vo > bv || (vo == bv && io < bi)) { bv = vo; bi = io; }
        }
        float e = expf(v0 - bv) + expf(v1 - bv);   // exp(-inf)=0 pads
        #pragma unroll
        for (int o = 32; o > 0; o >>= 1) e += __shfl_xor(e, o, 64);
        if (lane == 0) {
            out[262144 + row] = 1.0f / e;          // VG_scores
            out[262656 + row] = (float)bi;         // VG_scores_index
            ssel = bi;
        }
    }
    __syncthreads();

    // ---- block 511: sel-derived constants u / Gw / Bw
    if (row == 511) {
        const int sel = ssel;
        float gw = 0.f, bw = 0.f;
        #pragma unroll
        for (int c = tid; c < 1536; c += 512) {
            const float wv2 = W2[(size_t)c * 100 + sel];
            const float uu = lng[c] * wv2;
            u[c] = uu;
            gw += uu;
            bw += lnb[c] * wv2;
        }
        #pragma unroll
        for (int o = 32; o > 0; o >>= 1) {
            gw += __shfl_xor(gw, o, 64);
            bw += __shfl_xor(bw, o, 64);
        }
        if (lane == 0) { red16[wv] = gw; red16[8 + wv] = bw; }
        __syncthreads();
        if (tid == 0) {
            float G = 0.f, B = 0.f;
            #pragma unroll
            for (int i = 0; i < 8; ++i) { G += red16[i]; B += red16[8 + i]; }
            gwbw[0] = G;
            gwbw[1] = B + b2[sel];
        }
    }
}

// ---------------------------------------------------------------------------
// gemm1p: [32768,768]x[768,1536], 128x128 tile, BK=64, 12 K-tiles.
// BOTH operands bf16, staged via global_load_lds with the 16B-granule XOR
// swizzle (gcol = col ^ (row&7), 8 granules/row): read lanes hit every bank
// exactly 2x (free on gfx950). One ds_read_b128 per fragment, no casts.
// Epilogue: LDS round-trip stats (S1,S2,D). No act matrix.
// Measured r20/r22: ~103 us, 745 TF, MfmaUtil 34, VALUBusy 51. UNCHANGED.
// ---------------------------------------------------------------------------
__global__ __launch_bounds__(256) void gemm1p(
        const bf16_t* __restrict__ A, const bf16_t* __restrict__ Bt,
        const float* __restrict__ bias, const float* __restrict__ u,
        float* __restrict__ pS1, float* __restrict__ pS2,
        float* __restrict__ pD) {
    constexpr int K = 768;
    __shared__ alignas(16) char smem[36864];   // sA 16KB | sB 16KB; epi 36KB
    bf16_t* sA = (bf16_t*)smem;                // [128][64] bf16, swizzled
    bf16_t* sB = (bf16_t*)(smem + 16384);      // [128][64] bf16, swizzled

    // XCD-aware remap: 12 n-tiles of one m-tile land on one XCD
    const int linear = blockIdx.x + gridDim.x * blockIdx.y;
    const int xcd  = linear & 7;
    const int slot = linear >> 3;
    const int bx = slot % gridDim.x;
    const int by = (slot / gridDim.x) * 8 + xcd;

    const int tid  = threadIdx.x;
    const int lane = tid & 63;
    const int wave = tid >> 6;
    const int wr = wave >> 1, wc = wave & 1;
    const int m0 = by * 128;
    const int n0 = bx * 128;
    const int q  = lane >> 4;
    const int l15 = lane & 15;

    // ---- staging bases (A and B identical structure; 8 granules/row,
    //      swizzle gcol = col ^ (row&7); LDS dest linear, wave-uniform base)
    const bf16_t* gA[4]; bf16_t* lA[4];
    const bf16_t* gB[4]; bf16_t* lB[4];
    #pragma unroll
    for (int c = 0; c < 4; ++c) {
        const int s    = c * 256 + tid;
        const int row  = s >> 3;
        const int col  = s & 7;
        const int gcol = col ^ (row & 7);
        gA[c] = A  + (size_t)(m0 + row) * K + gcol * 8;
        lA[c] = sA + (c * 256 + wave * 64) * 8;
        gB[c] = Bt + (size_t)(n0 + row) * K + gcol * 8;
        lB[c] = sB + (c * 256 + wave * 64) * 8;
    }
    // ---- read bases (K-step invariant); row&7 == lane&7 for both
    const bf16_t* rA[4]; const bf16_t* rB[4];
    #pragma unroll
    for (int t4 = 0; t4 < 4; ++t4) {
        rA[t4] = sA + (wr * 64 + t4 * 16 + l15) * 64;
        rB[t4] = sB + (wc * 64 + t4 * 16 + l15) * 64;
    }
    const int c0 = ((q)     ^ (lane & 7)) * 8;   // ks=0 fragment offset
    const int c1 = ((4 + q) ^ (lane & 7)) * 8;   // ks=1 fragment offset

    floatx4 acc[4][4] = {};

    #pragma unroll
    for (int kt = 0; kt < 12; ++kt) {
        const int k0 = kt * 64;
        __syncthreads();   // prev compute done before LDS overwrite
        #pragma unroll
        for (int c = 0; c < 4; ++c) gl_lds16(gB[c] + k0, lB[c]);
        #pragma unroll
        for (int c = 0; c < 4; ++c) gl_lds16(gA[c] + k0, lA[c]);
        __syncthreads();   // drain DMA, then barrier

        #pragma unroll
        for (int ks = 0; ks < 2; ++ks) {
            const int co = ks ? c1 : c0;
            bf16x8 af[4], bfr[4];
            #pragma unroll
            for (int t4 = 0; t4 < 4; ++t4) {
                af[t4]  = *(const bf16x8*)(rA[t4] + co);
                bfr[t4] = *(const bf16x8*)(rB[t4] + co);
            }
            #pragma unroll
            for (int mt = 0; mt < 4; ++mt)
                #pragma unroll
                for (int nt = 0; nt < 4; ++nt)
                    acc[mt][nt] = __builtin_amdgcn_mfma_f32_16x16x32_bf16(
                        af[mt], bfr[nt], acc[mt][nt], 0, 0, 0);
        }
    }

    // ---- stats epilogue via LDS (low VGPR). C/D layout: col=l15, row=q*4+r.
    __syncthreads();                       // all tile ds_reads done
    bf16_t* sh = (bf16_t*)smem;            // [128][130] bf16 = 33280 B
    float*  su = (float*)(smem + 33280);   // u[n0..n0+127]          512 B
    float*  sp = (float*)(smem + 33792);   // [256][3] partials     3072 B

    if (tid < 128) su[tid] = u[n0 + tid];
    float bias4[4];
    #pragma unroll
    for (int nt = 0; nt < 4; ++nt) bias4[nt] = bias[n0 + wc * 64 + nt * 16 + l15];

    #pragma unroll
    for (int mt = 0; mt < 4; ++mt)
        #pragma unroll
        for (int nt = 0; nt < 4; ++nt)
            #pragma unroll
            for (int r = 0; r < 4; ++r) {
                const int rowl = wr * 64 + mt * 16 + q * 4 + r;
                const int coll = wc * 64 + nt * 16 + l15;
                sh[rowl * 130 + coll] = (bf16_t)gelu_fast(acc[mt][nt][r] + bias4[nt]);
            }
    __syncthreads();

    // phase 2: thread = (row, half); reduce 64 cols each
    {
        const int rowl = tid >> 1, half = tid & 1;
        const bf16_t* hp = sh + rowl * 130 + half * 64;
        const float*  up = su + half * 64;
        float s1 = 0.f, s2 = 0.f, dd = 0.f;
        #pragma unroll
        for (int c = 0; c < 64; ++c) {
            const float v = (float)hp[c];
            s1 += v; s2 += v * v; dd += v * up[c];
        }
        sp[tid * 3 + 0] = s1; sp[tid * 3 + 1] = s2; sp[tid * 3 + 2] = dd;
    }
    __syncthreads();
    if (tid < 128) {
        const float* p0 = sp + (2 * tid) * 3;
        const float* p1 = sp + (2 * tid + 1) * 3;
        const size_t idx = (size_t)bx * 32768 + (m0 + tid);
        pS1[idx] = p0[0] + p1[0];
        pS2[idx] = p0[1] + p1[1];
        pD[idx]  = p0[2] + p1[2];
    }
}

// ---------------------------------------------------------------------------
// out_scores: out[t*8+k] = rstd*(D - mu*Gw) + Bw   (32768 threads)
// ---------------------------------------------------------------------------
__global__ __launch_bounds__(256) void out_scores(
        const float* __restrict__ pS1, const float* __restrict__ pS2,
        const float* __restrict__ pD,  const float* __restrict__ gwbw,
        float* __restrict__ out) {
    const int t = blockIdx.x * 256 + threadIdx.x;   // 32768 exactly
    float s1 = 0.f, s2 = 0.f, d = 0.f;
    #pragma unroll
    for (int nt = 0; nt < 12; ++nt) {
        const size_t idx = (size_t)nt * 32768 + t;
        s1 += pS1[idx]; s2 += pS2[idx]; d += pD[idx];
    }
    const float mu   = s1 * (1.0f / 1536.0f);
    const float var  = s2 * (1.0f / 1536.0f) - mu * mu;
    const float rstd = rsqrtf(var + 1e-12f);
    const float v = rstd * (d - mu * gwbw[0]) + gwbw[1];
    const float4 f = make_float4(v, v, v, v);
    float4* o = (float4*)(out + (size_t)t * 8);
    o[0] = f; o[1] = f;
}

// ---------------------------------------------------------------------------
extern "C" void kernel_launch(void* const* d_in, const int* in_sizes, int n_in,
                              void* d_out, int out_size, void* d_ws, size_t ws_size,
                              hipStream_t stream) {
    const float* E   = (const float*)d_in[0];
    const float* W1  = (const float*)d_in[1];
    const float* b1  = (const float*)d_in[2];
    const float* lng = (const float*)d_in[3];
    const float* lnb = (const float*)d_in[4];
    const float* W2  = (const float*)d_in[5];
    const float* b2  = (const float*)d_in[6];
    float* out = (float*)d_out;

    char* w = (char*)d_ws;
    auto carve = [&](size_t bytes) {
        void* p = (void*)w;
        w += (bytes + 255) & ~(size_t)255;
        return p;
    };
    bf16_t* W1t   = (bf16_t*)carve((size_t)1536 * 768 * 2);    //  2.4 MB
    bf16_t* Ebf   = (bf16_t*)carve((size_t)32768 * 768 * 2);   // 50.3 MB
    float*  u     = (float*)carve(1536 * 4);
    float*  gwbw  = (float*)carve(256);
    // Union region: hpart (12.6 MB, written by prep_duo, dead after
    // own_lnlog) overlaps pS1/pS2/pD (4.7 MB, first written by gemm1p,
    // which runs after own_lnlog) — disjoint lifetimes.
    char*   unionr = (char*)carve((size_t)4 * 512 * 1536 * 4); // 12.6 MB
    float*  hpart = (float*)unionr;
    float*  pS1   = (float*)unionr;
    float*  pS2   = (float*)(unionr + (size_t)12 * 32768 * 4);
    float*  pD    = (float*)(unionr + (size_t)24 * 32768 * 4);

    // 1) prep: W1 transpose + own-row k-partials + E->bf16 (fused grid)
    prep_duo<<<12832, 256, 0, stream>>>(E, W1, W1t, hpart, Ebf);
    // 2) own rows: gelu+LN+logits+softmax/argmax; block 511 -> u/Gw/Bw
    own_lnlog<<<512, 512, 0, stream>>>(hpart, b1, lng, lnb, W2, b2,
                                       out, u, gwbw);
    // 3) fused GEMM, both operands bf16 via async DMA
    gemm1p<<<dim3(12, 256), 256, 0, stream>>>(Ebf, W1t, b1, u, pS1, pS2, pD);
    // 4) combine partials -> output 0
    out_scores<<<128, 256, 0, stream>>>(pS1, pS2, pD, gwbw, out);
}